// Round 8
// baseline (541.315 us; speedup 1.0000x reference)
//
#include <hip/hip_runtime.h>

// Problem geometry (compile-time constants from the reference)
#define N_TOTAL 500000
#define C 128
#define G 32
#define NB 8
#define EPS 1e-5f
#define NBLOCKS 2048
#define RPB ((N_TOTAL + NBLOCKS - 1) / NBLOCKS)   // 245 rows per block
#define NCTR 64
#define BLK_PER_CTR (NBLOCKS / NCTR)              // 32 blocks per arrival line

typedef float f4 __attribute__((ext_vector_type(4)));

// cumulative boundaries of LENGTHS = {40000,55000,70000,45000,80000,65000,90000,55000}
__device__ __forceinline__ int cloud_of(int i) {
    int c = 0;
    c += (i >= 40000);
    c += (i >= 95000);
    c += (i >= 165000);
    c += (i >= 210000);
    c += (i >= 290000);
    c += (i >= 355000);
    c += (i >= 445000);
    return c;
}

// element counts per (cloud, group) = LENGTHS[b] * (C/G)
__device__ const float d_cnt[NB] = {160000.f, 220000.f, 280000.f, 180000.f,
                                    320000.f, 260000.f, 360000.f, 220000.f};

// d_ws layout (bytes):
//   [0,     2048) : float ws[512]  (sum[8][32], sumsq[8][32])
//   [2048, 10240) : 64 arrival counters, one int per 128-B line
//   [10240,10368) : root counter
//   [10368,10496) : release flag
//   [16384, +N )  : cid[N_TOTAL] bytes (cloud id per original row)
#define CTR_OFF   (2048 / 4)
#define ROOT_OFF  (10240 / 4)
#define FLAG_OFF  (10368 / 4)
#define CID_OFF   16384

// accumulate one row into the 8 per-cloud register buckets (compile-time index)
#define ACCUM(v, cl)                                                          \
    do {                                                                      \
        float rs_ = (v).x + (v).y + (v).z + (v).w;                            \
        float rss_ = (v).x * (v).x + (v).y * (v).y + (v).z * (v).z +          \
                     (v).w * (v).w;                                           \
        _Pragma("unroll")                                                     \
        for (int b = 0; b < NB; b++)                                          \
            if ((cl) == b) { s[b] += rs_; ss[b] += rss_; }                    \
    } while (0)

// Prep: zero ws + barrier state, scatter cid[perm[i]] = cloud_of(i). ~3 MB.
// Its kernel boundary doubles as the phase-0 barrier.
__global__ __launch_bounds__(256) void gn_prep(const int* __restrict__ perm,
                                               int* __restrict__ wsi,
                                               unsigned char* __restrict__ cid) {
    int gid = blockIdx.x * 256 + threadIdx.x;
    if (gid < 10496 / 4) wsi[gid] = 0;   // ws + counters + root + flag
    for (int i = gid; i < N_TOTAL; i += 512 * 256)
        cid[perm[i]] = (unsigned char)cloud_of(i);
}

__global__ __launch_bounds__(256, 8) void gn_fused(const float* __restrict__ feats,
                                                   const float* __restrict__ gamma,
                                                   const float* __restrict__ beta,
                                                   float* __restrict__ ws,
                                                   const unsigned char* __restrict__ cid,
                                                   float* __restrict__ out) {
    const int tid = threadIdx.x;
    const int g = tid & 31;      // float4 slot (group) within row
    const int rsub = tid >> 5;   // 0..7 row-slot within 8-row stripe
    int start = blockIdx.x * RPB;
    int end = start + RPB;
    if (end > N_TOTAL) end = N_TOTAL;

    // ---------- phase 1: stats sweep (fills L2/L3 with feats) ----------
    __shared__ float lacc[2 * NB * G];
    for (int k = tid; k < 2 * NB * G; k += 256) lacc[k] = 0.f;
    __syncthreads();

    float s[NB], ss[NB];
#pragma unroll
    for (int b = 0; b < NB; b++) { s[b] = 0.f; ss[b] = 0.f; }

    int row = start + rsub;
    for (; row + 24 < end; row += 32) {
        int c0 = cid[row], c1 = cid[row + 8], c2 = cid[row + 16], c3 = cid[row + 24];
        f4 v0 = ((const f4*)(feats + ((long long)(row)      << 7)))[g];
        f4 v1 = ((const f4*)(feats + ((long long)(row + 8)  << 7)))[g];
        f4 v2 = ((const f4*)(feats + ((long long)(row + 16) << 7)))[g];
        f4 v3 = ((const f4*)(feats + ((long long)(row + 24) << 7)))[g];
        ACCUM(v0, c0); ACCUM(v1, c1); ACCUM(v2, c2); ACCUM(v3, c3);
    }
    for (; row < end; row += 8) {
        int c0 = cid[row];
        f4 v0 = ((const f4*)(feats + ((long long)row << 7)))[g];
        ACCUM(v0, c0);
    }

#pragma unroll
    for (int b = 0; b < NB; b++) {
        if (s[b] != 0.f || ss[b] != 0.f) {
            atomicAdd(&lacc[b * G + g], s[b]);
            atomicAdd(&lacc[NB * G + b * G + g], ss[b]);
        }
    }
    __syncthreads();

    for (int k = tid; k < 2 * NB * G; k += 256) {
        float a = lacc[k];
        if (a != 0.f) atomicAdd(&ws[k], a);
    }

    // ---------- hierarchical grid barrier ----------
    // 2048 arrivals spread over 64 cachelines; last per line escalates to root;
    // root #63 releases the flag. Spin with device-scope acquire loads.
    __threadfence();          // drain this thread's ws atomics
    __syncthreads();          // whole block done with phase 1
    int* ctr  = (int*)ws + CTR_OFF;
    int* root = (int*)ws + ROOT_OFF;
    int* flag = (int*)ws + FLAG_OFF;
    if (tid == 0) {
        int line = (blockIdx.x & (NCTR - 1)) * 32;   // one int per 128-B line
        int a = __hip_atomic_fetch_add(&ctr[line], 1, __ATOMIC_ACQ_REL,
                                       __HIP_MEMORY_SCOPE_AGENT);
        if (a == BLK_PER_CTR - 1) {
            int r = __hip_atomic_fetch_add(root, 1, __ATOMIC_ACQ_REL,
                                           __HIP_MEMORY_SCOPE_AGENT);
            if (r == NCTR - 1) {
                __hip_atomic_store(flag, 1, __ATOMIC_RELEASE,
                                   __HIP_MEMORY_SCOPE_AGENT);
            }
        }
        while (__hip_atomic_load(flag, __ATOMIC_ACQUIRE,
                                 __HIP_MEMORY_SCOPE_AGENT) == 0) {
            __builtin_amdgcn_s_sleep(8);
        }
    }
    __syncthreads();

    // ---------- phase 2: finalize + apply ----------
    __shared__ float lmean[NB * G];
    __shared__ float linv[NB * G];
    {
        // device-scope loads: ws was written by other blocks' atomics
        float sm = __hip_atomic_load(&ws[tid], __ATOMIC_RELAXED,
                                     __HIP_MEMORY_SCOPE_AGENT);
        float sq = __hip_atomic_load(&ws[NB * G + tid], __ATOMIC_RELAXED,
                                     __HIP_MEMORY_SCOPE_AGENT);
        float cnt = d_cnt[tid >> 5];
        float m = sm / cnt;
        float var = sq / cnt - m * m;
        lmean[tid] = m;
        linv[tid] = rsqrtf(var + EPS);
    }
    __syncthreads();

    f4 gm = ((const f4*)gamma)[g];
    f4 bt = ((const f4*)beta)[g];

#define NORM1(v, cl, r)                                                       \
    do {                                                                      \
        float m_ = lmean[(cl) * G + g];                                       \
        float i_ = linv[(cl) * G + g];                                        \
        f4 y_;                                                                \
        y_.x = ((v).x - m_) * i_ * gm.x + bt.x;                               \
        y_.y = ((v).y - m_) * i_ * gm.y + bt.y;                               \
        y_.z = ((v).z - m_) * i_ * gm.z + bt.z;                               \
        y_.w = ((v).w - m_) * i_ * gm.w + bt.w;                               \
        __builtin_nontemporal_store(y_, (f4*)(out + ((long long)(r) << 7)) + g); \
    } while (0)

    row = start + rsub;
    for (; row + 24 < end; row += 32) {
        int c0 = cid[row], c1 = cid[row + 8], c2 = cid[row + 16], c3 = cid[row + 24];
        f4 v0 = ((const f4*)(feats + ((long long)(row)      << 7)))[g];
        f4 v1 = ((const f4*)(feats + ((long long)(row + 8)  << 7)))[g];
        f4 v2 = ((const f4*)(feats + ((long long)(row + 16) << 7)))[g];
        f4 v3 = ((const f4*)(feats + ((long long)(row + 24) << 7)))[g];
        NORM1(v0, c0, row);
        NORM1(v1, c1, row + 8);
        NORM1(v2, c2, row + 16);
        NORM1(v3, c3, row + 24);
    }
    for (; row < end; row += 8) {
        int c0 = cid[row];
        f4 v0 = ((const f4*)(feats + ((long long)row << 7)))[g];
        NORM1(v0, c0, row);
    }
#undef NORM1
}

// ---------------- fallback (plain 3-kernel path, known-good ~165 µs) --------
__global__ __launch_bounds__(256) void gn_stats_fb(const float* __restrict__ feats,
                                                   const unsigned char* __restrict__ cid,
                                                   float* __restrict__ ws) {
    __shared__ float lacc[2 * NB * G];
    int tid = threadIdx.x;
    for (int k = tid; k < 2 * NB * G; k += 256) lacc[k] = 0.f;
    __syncthreads();
    const int g = tid & 31;
    const int rsub = tid >> 5;
    int start = blockIdx.x * RPB;
    int end = start + RPB;
    if (end > N_TOTAL) end = N_TOTAL;
    float s[NB], ss[NB];
#pragma unroll
    for (int b = 0; b < NB; b++) { s[b] = 0.f; ss[b] = 0.f; }
    for (int row = start + rsub; row < end; row += 8) {
        int c0 = cid[row];
        f4 v0 = ((const f4*)(feats + ((long long)row << 7)))[g];
        ACCUM(v0, c0);
    }
#pragma unroll
    for (int b = 0; b < NB; b++) {
        if (s[b] != 0.f || ss[b] != 0.f) {
            atomicAdd(&lacc[b * G + g], s[b]);
            atomicAdd(&lacc[NB * G + b * G + g], ss[b]);
        }
    }
    __syncthreads();
    for (int k = tid; k < 2 * NB * G; k += 256) {
        float a = lacc[k];
        if (a != 0.f) atomicAdd(&ws[k], a);
    }
}

__global__ __launch_bounds__(256) void gn_apply_fb(const float* __restrict__ feats,
                                                   const unsigned char* __restrict__ cid,
                                                   const float* __restrict__ gamma,
                                                   const float* __restrict__ beta,
                                                   const float* __restrict__ ws,
                                                   float* __restrict__ out) {
    __shared__ float lmean[NB * G];
    __shared__ float linv[NB * G];
    int tid = threadIdx.x;
    {
        float sm = ws[tid];
        float sq = ws[NB * G + tid];
        float cnt = d_cnt[tid >> 5];
        float m = sm / cnt;
        float var = sq / cnt - m * m;
        lmean[tid] = m;
        linv[tid] = rsqrtf(var + EPS);
    }
    __syncthreads();
    const int g = tid & 31;
    const int rsub = tid >> 5;
    f4 gm = ((const f4*)gamma)[g];
    f4 bt = ((const f4*)beta)[g];
    int start = blockIdx.x * RPB;
    int end = start + RPB;
    if (end > N_TOTAL) end = N_TOTAL;
    for (int row = start + rsub; row < end; row += 8) {
        int cl = cid[row];
        f4 v = ((const f4*)(feats + ((long long)row << 7)))[g];
        float m = lmean[cl * G + g];
        float inv = linv[cl * G + g];
        f4 y;
        y.x = (v.x - m) * inv * gm.x + bt.x;
        y.y = (v.y - m) * inv * gm.y + bt.y;
        y.z = (v.z - m) * inv * gm.z + bt.z;
        y.w = (v.w - m) * inv * gm.w + bt.w;
        __builtin_nontemporal_store(y, (f4*)(out + ((long long)row << 7)) + g);
    }
}

extern "C" void kernel_launch(void* const* d_in, const int* in_sizes, int n_in,
                              void* d_out, int out_size, void* d_ws, size_t ws_size,
                              hipStream_t stream) {
    const float* feats = (const float*)d_in[0];
    const float* gamma = (const float*)d_in[1];
    const float* beta  = (const float*)d_in[2];
    const int*   perm  = (const int*)d_in[3];
    float* out = (float*)d_out;
    float* ws  = (float*)d_ws;
    unsigned char* cid = (unsigned char*)d_ws + CID_OFF;

    gn_prep<<<512, 256, 0, stream>>>(perm, (int*)d_ws, cid);

    void* args[] = {(void*)&feats, (void*)&gamma, (void*)&beta,
                    (void*)&ws, (void*)&cid, (void*)&out};
    hipError_t err = hipLaunchCooperativeKernel((const void*)gn_fused,
                                                dim3(NBLOCKS), dim3(256),
                                                args, 0, stream);
    if (err != hipSuccess) {
        // Deterministic fallback: plain kernels (no spin barrier — safe
        // without a co-residency guarantee).
        gn_stats_fb<<<NBLOCKS, 256, 0, stream>>>(feats, cid, ws);
        gn_apply_fb<<<NBLOCKS, 256, 0, stream>>>(feats, cid, gamma, beta, ws, out);
    }
}

// Round 9
// 372.696 us; speedup vs baseline: 1.4524x; 1.4524x over previous
//
#include <hip/hip_runtime.h>

// Problem geometry (compile-time constants from the reference)
#define N_TOTAL 500000
#define C 128
#define G 32
#define NB 8
#define EPS 1e-5f
#define NBLK 2048

typedef float f4 __attribute__((ext_vector_type(4)));

// ws layout: float ws[0..255] = sum[cloud][group], ws[256..511] = sumsq.

__global__ void gn_zero(float* __restrict__ ws) {
    int i = threadIdx.x;
    if (i < 2 * NB * G) ws[i] = 0.f;
}

// Per-cloud stats: rows of cloud `cloud` are perm[i], i in [i_begin, i_end).
// 32 lanes per row (one float4 = one group per lane), 8 rows per block-iter.
__global__ __launch_bounds__(256) void gn_stats_chunk(const float* __restrict__ feats,
                                                      const int* __restrict__ perm,
                                                      float* __restrict__ ws,
                                                      int i_begin, int i_end, int cloud) {
    __shared__ float lacc[2 * G];   // [0..31]=sum per group, [32..63]=sumsq
    int tid = threadIdx.x;
    if (tid < 2 * G) lacc[tid] = 0.f;
    __syncthreads();

    const int g = tid & 31;
    const int rsub = tid >> 5;
    float s = 0.f, ss = 0.f;
    for (int i = i_begin + blockIdx.x * 8 + rsub; i < i_end; i += NBLK * 8) {
        int p = perm[i];
        f4 v = ((const f4*)(feats + ((long long)p << 7)))[g];
        s  += v.x + v.y + v.z + v.w;
        ss += v.x * v.x + v.y * v.y + v.z * v.z + v.w * v.w;
    }
    atomicAdd(&lacc[g], s);
    atomicAdd(&lacc[G + g], ss);
    __syncthreads();

    if (tid < 2 * G) {
        float a = lacc[tid];
        if (a != 0.f) {
            float* dst = (tid < G) ? &ws[cloud * G + tid]
                                   : &ws[NB * G + cloud * G + (tid - G)];
            atomicAdd(dst, a);
        }
    }
}

// Per-cloud apply: finalize this cloud's 32 group stats, then normalize+affine.
// feats rows were read by the matching stats kernel one launch earlier ->
// cache-served. nt stores keep `out` from evicting upcoming clouds' feats.
__global__ __launch_bounds__(256) void gn_apply_chunk(const float* __restrict__ feats,
                                                      const int* __restrict__ perm,
                                                      const float* __restrict__ gamma,
                                                      const float* __restrict__ beta,
                                                      const float* __restrict__ ws,
                                                      float* __restrict__ out,
                                                      int i_begin, int i_end,
                                                      float inv_cnt, int cloud) {
    __shared__ float lmean[G];
    __shared__ float linv[G];
    int tid = threadIdx.x;
    if (tid < G) {
        float sm = ws[cloud * G + tid];
        float sq = ws[NB * G + cloud * G + tid];
        float m = sm * inv_cnt;
        float var = sq * inv_cnt - m * m;
        lmean[tid] = m;
        linv[tid] = rsqrtf(var + EPS);
    }
    __syncthreads();

    const int g = tid & 31;
    const int rsub = tid >> 5;
    float m = lmean[g];
    float inv = linv[g];
    f4 gm = ((const f4*)gamma)[g];
    f4 bt = ((const f4*)beta)[g];

    for (int i = i_begin + blockIdx.x * 8 + rsub; i < i_end; i += NBLK * 8) {
        int p = perm[i];
        f4 v = ((const f4*)(feats + ((long long)p << 7)))[g];
        f4 y;
        y.x = (v.x - m) * inv * gm.x + bt.x;
        y.y = (v.y - m) * inv * gm.y + bt.y;
        y.z = (v.z - m) * inv * gm.z + bt.z;
        y.w = (v.w - m) * inv * gm.w + bt.w;
        __builtin_nontemporal_store(y, (f4*)(out + ((long long)p << 7)) + g);
    }
}

extern "C" void kernel_launch(void* const* d_in, const int* in_sizes, int n_in,
                              void* d_out, int out_size, void* d_ws, size_t ws_size,
                              hipStream_t stream) {
    const float* feats = (const float*)d_in[0];
    const float* gamma = (const float*)d_in[1];
    const float* beta  = (const float*)d_in[2];
    const int*   perm  = (const int*)d_in[3];
    float* out = (float*)d_out;
    float* ws  = (float*)d_ws;

    // cumulative boundaries of LENGTHS and per-(cloud,group) element counts
    static const int bounds[NB + 1] = {0, 40000, 95000, 165000, 210000,
                                       290000, 355000, 445000, 500000};
    static const float inv_cnt[NB] = {1.f / 160000.f, 1.f / 220000.f,
                                      1.f / 280000.f, 1.f / 180000.f,
                                      1.f / 320000.f, 1.f / 260000.f,
                                      1.f / 360000.f, 1.f / 220000.f};

    gn_zero<<<1, 512, 0, stream>>>(ws);

    // Software-pipelined interleave: S0, S1, A0, S2, A1, ..., S7, A6, A7.
    // A_k runs one launch after S_k -> short reuse distance for feats.
    gn_stats_chunk<<<NBLK, 256, 0, stream>>>(feats, perm, ws,
                                             bounds[0], bounds[1], 0);
    for (int k = 1; k < NB; ++k) {
        gn_stats_chunk<<<NBLK, 256, 0, stream>>>(feats, perm, ws,
                                                 bounds[k], bounds[k + 1], k);
        gn_apply_chunk<<<NBLK, 256, 0, stream>>>(feats, perm, gamma, beta, ws, out,
                                                 bounds[k - 1], bounds[k],
                                                 inv_cnt[k - 1], k - 1);
    }
    gn_apply_chunk<<<NBLK, 256, 0, stream>>>(feats, perm, gamma, beta, ws, out,
                                             bounds[NB - 1], bounds[NB],
                                             inv_cnt[NB - 1], NB - 1);
}

// Round 10
// 170.343 us; speedup vs baseline: 3.1778x; 2.1879x over previous
//
#include <hip/hip_runtime.h>

// Problem geometry (compile-time constants from the reference)
#define N_TOTAL 500000
#define C 128
#define G 32
#define NB 8
#define EPS 1e-5f
#define NBLK 2048
#define RPB ((N_TOTAL + NBLK - 1) / NBLK)   // 245 rows per block

typedef float f4 __attribute__((ext_vector_type(4)));

// cumulative boundaries of LENGTHS = {40000,55000,70000,45000,80000,65000,90000,55000}
__device__ __forceinline__ int cloud_of(int i) {
    int c = 0;
    c += (i >= 40000);
    c += (i >= 95000);
    c += (i >= 165000);
    c += (i >= 210000);
    c += (i >= 290000);
    c += (i >= 355000);
    c += (i >= 445000);
    return c;
}

// element counts per (cloud, group) = LENGTHS[b] * (C/G)
__device__ const float d_cnt[NB] = {160000.f, 220000.f, 280000.f, 180000.f,
                                    320000.f, 260000.f, 360000.f, 220000.f};

// ws layout: float ws[0..255] = sum[cloud][group], ws[256..511] = sumsq.

__global__ void gn_zero(float* __restrict__ ws) {
    int i = threadIdx.x;
    if (i < 2 * NB * G) ws[i] = 0.f;
}

// process one row's float4 with running (cur, s, ss); flush on cloud change
#define PROC(r, v)                                                            \
    do {                                                                      \
        int cl_ = cloud_of(r);                                                \
        if (cl_ != cur) {                                                     \
            if (cur >= 0) {                                                   \
                atomicAdd(&lacc[cur * G + g], s);                             \
                atomicAdd(&lacc[NB * G + cur * G + g], ss);                   \
            }                                                                 \
            cur = cl_; s = 0.f; ss = 0.f;                                     \
        }                                                                     \
        s  += (v).x + (v).y + (v).z + (v).w;                                  \
        ss += (v).x * (v).x + (v).y * (v).y + (v).z * (v).z + (v).w * (v).w;  \
    } while (0)

// Stats: rows perm[i] for i in block's span; 32 lanes per row (one float4 each),
// 8 rows per 256-thread iteration, 4 independent row-loads in flight.
__global__ __launch_bounds__(256) void gn_stats(const float* __restrict__ feats,
                                                const int* __restrict__ perm,
                                                float* __restrict__ ws) {
    __shared__ float lacc[2 * NB * G];
    int tid = threadIdx.x;
    for (int k = tid; k < 2 * NB * G; k += 256) lacc[k] = 0.f;
    __syncthreads();

    const int g = tid & 31;
    const int rsub = tid >> 5;
    int start = blockIdx.x * RPB;
    int end = start + RPB;
    if (end > N_TOTAL) end = N_TOTAL;

    float s = 0.f, ss = 0.f;
    int cur = -1;

    int row = start + rsub;
    for (; row + 24 < end; row += 32) {
        int p0 = perm[row], p1 = perm[row + 8], p2 = perm[row + 16], p3 = perm[row + 24];
        f4 v0 = ((const f4*)(feats + ((long long)p0 << 7)))[g];
        f4 v1 = ((const f4*)(feats + ((long long)p1 << 7)))[g];
        f4 v2 = ((const f4*)(feats + ((long long)p2 << 7)))[g];
        f4 v3 = ((const f4*)(feats + ((long long)p3 << 7)))[g];
        PROC(row, v0); PROC(row + 8, v1); PROC(row + 16, v2); PROC(row + 24, v3);
    }
    for (; row < end; row += 8) {
        int p0 = perm[row];
        f4 v0 = ((const f4*)(feats + ((long long)p0 << 7)))[g];
        PROC(row, v0);
    }
    if (cur >= 0) {
        atomicAdd(&lacc[cur * G + g], s);
        atomicAdd(&lacc[NB * G + cur * G + g], ss);
    }
    __syncthreads();

    for (int k = tid; k < 2 * NB * G; k += 256) {
        float a = lacc[k];
        if (a != 0.f) atomicAdd(&ws[k], a);
    }
}

// Apply: finalize stats in LDS, then normalize+affine rows perm[i]; plain
// stores (L3 is memory-side; ascending order is already LRU-friendly).
__global__ __launch_bounds__(256) void gn_apply(const float* __restrict__ feats,
                                                const int* __restrict__ perm,
                                                const float* __restrict__ gamma,
                                                const float* __restrict__ beta,
                                                const float* __restrict__ ws,
                                                float* __restrict__ out) {
    __shared__ float lmean[NB * G];
    __shared__ float linv[NB * G];
    int tid = threadIdx.x;
    {
        float sm = ws[tid];
        float sq = ws[NB * G + tid];
        float cnt = d_cnt[tid >> 5];
        float m = sm / cnt;
        float var = sq / cnt - m * m;
        lmean[tid] = m;
        linv[tid] = rsqrtf(var + EPS);
    }
    __syncthreads();

    const int g = tid & 31;
    const int rsub = tid >> 5;
    f4 gm = ((const f4*)gamma)[g];
    f4 bt = ((const f4*)beta)[g];

    int start = blockIdx.x * RPB;
    int end = start + RPB;
    if (end > N_TOTAL) end = N_TOTAL;

#define NORM1(r, p, v)                                                        \
    do {                                                                      \
        int cl_ = cloud_of(r);                                                \
        float m_ = lmean[cl_ * G + g];                                        \
        float i_ = linv[cl_ * G + g];                                         \
        f4 y_;                                                                \
        y_.x = ((v).x - m_) * i_ * gm.x + bt.x;                               \
        y_.y = ((v).y - m_) * i_ * gm.y + bt.y;                               \
        y_.z = ((v).z - m_) * i_ * gm.z + bt.z;                               \
        y_.w = ((v).w - m_) * i_ * gm.w + bt.w;                               \
        ((f4*)(out + ((long long)(p) << 7)))[g] = y_;                         \
    } while (0)

    int row = start + rsub;
    for (; row + 24 < end; row += 32) {
        int p0 = perm[row], p1 = perm[row + 8], p2 = perm[row + 16], p3 = perm[row + 24];
        f4 v0 = ((const f4*)(feats + ((long long)p0 << 7)))[g];
        f4 v1 = ((const f4*)(feats + ((long long)p1 << 7)))[g];
        f4 v2 = ((const f4*)(feats + ((long long)p2 << 7)))[g];
        f4 v3 = ((const f4*)(feats + ((long long)p3 << 7)))[g];
        NORM1(row, p0, v0);
        NORM1(row + 8, p1, v1);
        NORM1(row + 16, p2, v2);
        NORM1(row + 24, p3, v3);
    }
    for (; row < end; row += 8) {
        int p0 = perm[row];
        f4 v0 = ((const f4*)(feats + ((long long)p0 << 7)))[g];
        NORM1(row, p0, v0);
    }
#undef NORM1
}

extern "C" void kernel_launch(void* const* d_in, const int* in_sizes, int n_in,
                              void* d_out, int out_size, void* d_ws, size_t ws_size,
                              hipStream_t stream) {
    const float* feats = (const float*)d_in[0];
    const float* gamma = (const float*)d_in[1];
    const float* beta  = (const float*)d_in[2];
    const int*   perm  = (const int*)d_in[3];
    float* out = (float*)d_out;
    float* ws  = (float*)d_ws;

    gn_zero<<<1, 512, 0, stream>>>(ws);
    gn_stats<<<NBLK, 256, 0, stream>>>(feats, perm, ws);
    gn_apply<<<NBLK, 256, 0, stream>>>(feats, perm, gamma, beta, ws, out);
}